// Round 15
// baseline (1678.764 us; speedup 1.0000x reference)
//
#include <hip/hip_runtime.h>

// RLIF forward, persistent kernel, stamp-in-word sync.
// Round 15 = Round 14 (PASS @1230us, register-Wr) with ONE change: the poll
// block swaps R6's serialized-guarded shape for R8/R10's batched shape with
// s_sleep(16) (~1024cy) backoff instead of sleep(1)/hot.
//  Model (fits R6/R8/R10/R12/R13/R14): serialized poll pays an 8-RTT final
//  detect pass (~2us even at zero skew); batched pays 1 RTT but R8/R10's
//  ~600cy re-sample period congested the fabric (+80MB FETCH) and delayed the
//  publishes. Batched + long backoff gets the 1-RTT final pass WITHOUT the
//  storm. Discriminator: FETCH_SIZE must stay ~R6-level (<=210MB).
// Datapath (register 3-split Wr, A-frag bits, single mat-outer/ks-inner MFMA
// chain, epilogue order), publish, triple buffer: byte-identical to R14.

#define T_STEPS 256
#define BATCH   128
#define NNEUR   1024
#define DECAY_F 0.2f
#define THRESH  0.3f

typedef __attribute__((ext_vector_type(8))) short short8;
typedef __attribute__((ext_vector_type(4))) float f32x4;

union FU { short8 s; unsigned u[4]; };
union S8 { short8 s; unsigned short us[8]; };

__device__ __forceinline__ unsigned short f2bf_rn(float x) {
    unsigned u = __float_as_uint(x);
    return (unsigned short)((u + 0x7FFFu + ((u >> 16) & 1u)) >> 16);
}

__global__ void rlif_init(unsigned* __restrict__ ybits) {
    int i = blockIdx.x * 256 + threadIdx.x;
    if (i < 3 * BATCH * 64) ybits[i] = 0xFFFF0000u;   // stamp 0xFFFF: never matches t
}

__global__ __launch_bounds__(256, 1)
void rlif_persist(const float* __restrict__ tx,   // [T][B][N]
                  const float* __restrict__ Wr,   // [N][N]
                  const float* __restrict__ br,   // [N]
                  float* __restrict__ out,        // [T][B][N]
                  unsigned* __restrict__ ybits)   // [3][128][64] stamped words
{
    extern __shared__ char smem[];
    float* red = (float*)smem;                                // [2][16][16] f32
    unsigned short* ys = (unsigned short*)(smem + 2*16*16*4); // [32][66]

    const int tid = threadIdx.x;
    const int bb  = blockIdx.x >> 6;   // 0..3  batch-block (32 batches)
    const int ib  = blockIdx.x & 63;   // 0..63 neuron-block (16 neurons)
    const int i0  = ib * 16;
    const int b0  = bb * 32;
    const int w   = tid >> 6;          // wave 0..3
    const int l   = tid & 63;
    const int c   = l & 15;
    const int kg  = l >> 4;
    const int r   = w & 1;             // row-tile
    const int h   = w >> 1;            // k-half

    // ---- one-time: this lane's Wr B-fragments, exact 3-way bf16 split, in regs ----
    short8 fr0[16], fr1[16], fr2[16];
    {
        const float* wrow = Wr + (size_t)(i0 + c) * NNEUR + h * 512 + kg * 8;
        #pragma unroll
        for (int ks = 0; ks < 16; ++ks) {
            float4 a = *(const float4*)(wrow + ks * 32);
            float4 b = *(const float4*)(wrow + ks * 32 + 4);
            float fv[8] = {a.x, a.y, a.z, a.w, b.x, b.y, b.z, b.w};
            S8 vh, vm, vl;
            #pragma unroll
            for (int e = 0; e < 8; ++e) {
                float fw = fv[e];
                unsigned short hb = f2bf_rn(fw);
                float hf = __uint_as_float((unsigned)hb << 16);
                float rm = fw - hf;                     // exact (Sterbenz)
                unsigned short mb = f2bf_rn(rm);
                float mf = __uint_as_float((unsigned)mb << 16);
                float rl = rm - mf;                     // exact; fits bf16
                vh.us[e] = hb; vm.us[e] = mb; vl.us[e] = f2bf_rn(rl);
            }
            fr0[ks] = vh.s; fr1[ks] = vm.s; fr2[ks] = vl.s;
        }
    }
    __syncthreads();

    const float brv = br[i0 + c];
    float vreg[4] = {0.f, 0.f, 0.f, 0.f};
    const size_t BN = (size_t)BATCH * NNEUR;

    // poll geometry (R8/R10): thread owns col-pair cp, rows rb, rb+8, rb+16, rb+24
    const int cp = tid & 31;
    const int rb = tid >> 5;

    for (int t = 0; t < T_STEPS; ++t) {
        float txv[4];
        if (w < 2) {
            #pragma unroll
            for (int j = 0; j < 4; ++j)
                txv[j] = tx[(size_t)t * BN + (size_t)(b0 + w * 16 + kg * 4 + j) * NNEUR + i0 + c];
        }

        // ---- stage spikes of step t-1: batched stamped-qword poll + sleep(16) ----
        if (t > 0) {
            unsigned long long* qb64 =
                (unsigned long long*)(ybits + (size_t)((t - 1) % 3) * (BATCH * 64));
            const unsigned want = (unsigned)(t - 1);
            unsigned pend = 0xFu;
            for (;;) {
                unsigned long long qv[4];
                #pragma unroll
                for (int k = 0; k < 4; ++k)
                    qv[k] = __hip_atomic_load(qb64 + (size_t)(b0 + rb + 8 * k) * 32 + cp,
                                              __ATOMIC_RELAXED, __HIP_MEMORY_SCOPE_AGENT);
                #pragma unroll
                for (int k = 0; k < 4; ++k) {
                    if (pend & (1u << k)) {
                        unsigned lo = (unsigned)qv[k];
                        unsigned hi = (unsigned)(qv[k] >> 32);
                        if (((lo >> 16) == want) & ((hi >> 16) == want)) {
                            *(unsigned*)&ys[(rb + 8 * k) * 66 + 2 * cp] =
                                (lo & 0xFFFFu) | (hi << 16);
                            pend &= ~(1u << k);
                        }
                    }
                }
                if (!pend) break;
                __builtin_amdgcn_s_sleep(16);   // ~1024cy backoff: kill the re-poll storm
            }
        }
        __syncthreads();

        f32x4 acc = {0.f, 0.f, 0.f, 0.f};
        if (t > 0) {
            // A-frags: bf16 1.0 / 0.0 bit patterns (identical to rounds 2/5/6/14)
            short8 afr[16];
            #pragma unroll
            for (int ks = 0; ks < 16; ++ks) {
                unsigned wv = *(const unsigned*)(ys + (r * 16 + c) * 66 + 2 * (h * 16 + ks));
                unsigned byt = (wv >> (kg * 8)) & 0xFFu;
                FU f;
                #pragma unroll
                for (int q = 0; q < 4; ++q) {
                    f.u[q] = (((byt >> (2 * q)) & 1u) ? 0x00003F80u : 0u)
                           | (((byt >> (2 * q + 1)) & 1u) ? 0x3F800000u : 0u);
                }
                afr[ks] = f.s;
            }
            // single accumulator chain, mat-outer / ks-inner — proven exact order
            #pragma unroll
            for (int ks = 0; ks < 16; ++ks)
                acc = __builtin_amdgcn_mfma_f32_16x16x32_bf16(afr[ks], fr0[ks], acc, 0, 0, 0);
            #pragma unroll
            for (int ks = 0; ks < 16; ++ks)
                acc = __builtin_amdgcn_mfma_f32_16x16x32_bf16(afr[ks], fr1[ks], acc, 0, 0, 0);
            #pragma unroll
            for (int ks = 0; ks < 16; ++ks)
                acc = __builtin_amdgcn_mfma_f32_16x16x32_bf16(afr[ks], fr2[ks], acc, 0, 0, 0);
        }

        if (w >= 2) {
            #pragma unroll
            for (int j = 0; j < 4; ++j)
                red[r * 256 + (kg * 4 + j) * 16 + c] = acc[j];
        }
        __syncthreads();

        if (w < 2) {
            float* op = out + (size_t)t * BN;
            unsigned* pbuf = ybits + (size_t)(t % 3) * (BATCH * 64);
            #pragma unroll
            for (int j = 0; j < 4; ++j) {
                float z  = acc[j] + red[w * 256 + (kg * 4 + j) * 16 + c];
                float x  = (txv[j] + z) + brv;
                float vv = DECAY_F * vreg[j] + x;
                int   sp = vv > THRESH;
                vreg[j]  = sp ? 0.f : vv;
                op[(size_t)(b0 + w * 16 + kg * 4 + j) * NNEUR + i0 + c] = sp ? 1.f : 0.f;
                unsigned long long m = __ballot(sp != 0);
                if (c == j) {
                    unsigned u16v = (unsigned)((m >> (kg * 16)) & 0xFFFFu);
                    atomicExch(&pbuf[(b0 + w * 16 + kg * 4 + j) * 64 + ib],
                               ((unsigned)t << 16) | u16v);
                }
            }
        }
        // no end-of-step barrier: stamp polling is the synchronization
    }
}

extern "C" void kernel_launch(void* const* d_in, const int* in_sizes, int n_in,
                              void* d_out, int out_size, void* d_ws, size_t ws_size,
                              hipStream_t stream)
{
    const float* tx = (const float*)d_in[0];
    const float* Wr = (const float*)d_in[1];
    const float* br = (const float*)d_in[2];
    float* out = (float*)d_out;
    unsigned* ybits = (unsigned*)d_ws;   // [3][128][64] u32 = 96 KB

    const int lds_bytes = 2 * 16 * 16 * 4 + 32 * 66 * 2;   // 6272
    hipFuncSetAttribute(reinterpret_cast<const void*>(rlif_persist),
                        hipFuncAttributeMaxDynamicSharedMemorySize, lds_bytes);

    rlif_init<<<dim3(96), dim3(256), 0, stream>>>(ybits);
    rlif_persist<<<dim3(256), dim3(256), lds_bytes, stream>>>(tx, Wr, br, out, ybits);
}

// Round 16
// 929.104 us; speedup vs baseline: 1.8069x; 1.8069x over previous
//
#include <hip/hip_runtime.h>

// RLIF forward, persistent kernel, stamp-in-word sync.
// Round 16 = Round 14 (PASS @1230us, register-Wr) with ONE structural change:
// group geometry 4x64 -> 8x32. wg = 16 batches x 32 neurons; waves = (ct,h)
// (neuron sub-tile, k-half) instead of (row-tile, k-half).
//  - producer set per group 64 -> 32 (skew tail shrinks)
//  - stamped words per group 2048 -> 1024 -> guarded poll chain 8 -> 4
//    (halves the worst-case serialized detect latency; poll SHAPE unchanged:
//    guarded serialized + sleep(1), the 5x-validated best)
//  - per-wave compute identical: 48 MFMA, 192 Wr VGPRs, same A-frag bits, same
//    mat-outer/ks-inner chain, z = acc_h0 + red_h1 -> bit-identical output.
// Publish (atomicExch (t<<16)|bits16, triple buffer) byte-identical.

#define T_STEPS 256
#define BATCH   128
#define NNEUR   1024
#define DECAY_F 0.2f
#define THRESH  0.3f

typedef __attribute__((ext_vector_type(8))) short short8;
typedef __attribute__((ext_vector_type(4))) float f32x4;

union FU { short8 s; unsigned u[4]; };
union S8 { short8 s; unsigned short us[8]; };

__device__ __forceinline__ unsigned short f2bf_rn(float x) {
    unsigned u = __float_as_uint(x);
    return (unsigned short)((u + 0x7FFFu + ((u >> 16) & 1u)) >> 16);
}

__global__ void rlif_init(unsigned* __restrict__ ybits) {
    int i = blockIdx.x * 256 + threadIdx.x;
    if (i < 3 * 8 * 1024) ybits[i] = 0xFFFF0000u;   // stamp 0xFFFF: never matches t
}

__global__ __launch_bounds__(256, 1)
void rlif_persist(const float* __restrict__ tx,   // [T][B][N]
                  const float* __restrict__ Wr,   // [N][N]
                  const float* __restrict__ br,   // [N]
                  float* __restrict__ out,        // [T][B][N]
                  unsigned* __restrict__ ybits)   // [3][8 grp][16 row][64 col] stamped
{
    extern __shared__ char smem[];
    float* red = (float*)smem;                                // [2 ct][16][16] f32
    unsigned short* ys = (unsigned short*)(smem + 2*16*16*4); // [16][66]

    const int tid = threadIdx.x;
    const int bb  = blockIdx.x >> 5;   // 0..7  batch-block (16 batches)
    const int ib  = blockIdx.x & 31;   // 0..31 neuron-block (32 neurons)
    const int i0  = ib * 32;
    const int b0  = bb * 16;
    const int w   = tid >> 6;          // wave 0..3
    const int l   = tid & 63;
    const int c   = l & 15;
    const int kg  = l >> 4;
    const int ct  = w & 1;             // neuron sub-tile (16 neurons)
    const int h   = w >> 1;            // k-half

    // ---- one-time: this lane's Wr B-fragments, exact 3-way bf16 split, in regs ----
    // wave (ct,h), lane (c,kg) holds Wr[i0+ct*16+c][h*512 + ks*32 + kg*8 ..+8], ks 0..15
    short8 fr0[16], fr1[16], fr2[16];
    {
        const float* wrow = Wr + (size_t)(i0 + ct * 16 + c) * NNEUR + h * 512 + kg * 8;
        #pragma unroll
        for (int ks = 0; ks < 16; ++ks) {
            float4 a = *(const float4*)(wrow + ks * 32);
            float4 b = *(const float4*)(wrow + ks * 32 + 4);
            float fv[8] = {a.x, a.y, a.z, a.w, b.x, b.y, b.z, b.w};
            S8 vh, vm, vl;
            #pragma unroll
            for (int e = 0; e < 8; ++e) {
                float fw = fv[e];
                unsigned short hb = f2bf_rn(fw);
                float hf = __uint_as_float((unsigned)hb << 16);
                float rm = fw - hf;                     // exact (Sterbenz)
                unsigned short mb = f2bf_rn(rm);
                float mf = __uint_as_float((unsigned)mb << 16);
                float rl = rm - mf;                     // exact; fits bf16
                vh.us[e] = hb; vm.us[e] = mb; vl.us[e] = f2bf_rn(rl);
            }
            fr0[ks] = vh.s; fr1[ks] = vm.s; fr2[ks] = vl.s;
        }
    }
    __syncthreads();

    const float brv = br[i0 + ct * 16 + c];
    float vreg[4] = {0.f, 0.f, 0.f, 0.f};
    const size_t BN = (size_t)BATCH * NNEUR;

    for (int t = 0; t < T_STEPS; ++t) {
        float txv[4];
        if (h == 0) {
            #pragma unroll
            for (int j = 0; j < 4; ++j)
                txv[j] = tx[(size_t)t * BN + (size_t)(b0 + kg * 4 + j) * NNEUR + i0 + ct * 16 + c];
        }

        // ---- stage spikes of step t-1 into LDS (R6 poll shape, chain of 4) ----
        if (t > 0) {
            unsigned* buf = ybits + (size_t)((t - 1) % 3) * (8 * 1024) + bb * 1024;
            const unsigned want = (unsigned)(t - 1);
            unsigned pend = 0xFu;     // 4 words per thread: wi = k*256 + tid
            for (;;) {
                #pragma unroll
                for (int k = 0; k < 4; ++k) {
                    if (pend & (1u << k)) {
                        int wi  = (k << 8) | tid;       // 0..1023
                        int row = wi >> 6;              // 0..15 (batch within block)
                        int col = wi & 63;              // writer column (ib*2+ct)
                        unsigned v = __hip_atomic_load(&buf[row * 64 + col],
                                                       __ATOMIC_RELAXED, __HIP_MEMORY_SCOPE_AGENT);
                        if ((v >> 16) == want) {
                            ys[row * 66 + col] = (unsigned short)(v & 0xFFFFu);
                            pend &= ~(1u << k);
                        }
                    }
                }
                if (!pend) break;
                __builtin_amdgcn_s_sleep(1);
            }
        }
        __syncthreads();

        f32x4 acc = {0.f, 0.f, 0.f, 0.f};
        if (t > 0) {
            // A-frags: bf16 1.0 / 0.0 bit patterns (identical to rounds 2/5/6/14)
            short8 afr[16];
            #pragma unroll
            for (int ks = 0; ks < 16; ++ks) {
                unsigned wv = *(const unsigned*)(ys + c * 66 + 2 * (h * 16 + ks));
                unsigned byt = (wv >> (kg * 8)) & 0xFFu;
                FU f;
                #pragma unroll
                for (int q = 0; q < 4; ++q) {
                    f.u[q] = (((byt >> (2 * q)) & 1u) ? 0x00003F80u : 0u)
                           | (((byt >> (2 * q + 1)) & 1u) ? 0x3F800000u : 0u);
                }
                afr[ks] = f.s;
            }
            // single accumulator chain, mat-outer / ks-inner — proven exact order
            #pragma unroll
            for (int ks = 0; ks < 16; ++ks)
                acc = __builtin_amdgcn_mfma_f32_16x16x32_bf16(afr[ks], fr0[ks], acc, 0, 0, 0);
            #pragma unroll
            for (int ks = 0; ks < 16; ++ks)
                acc = __builtin_amdgcn_mfma_f32_16x16x32_bf16(afr[ks], fr1[ks], acc, 0, 0, 0);
            #pragma unroll
            for (int ks = 0; ks < 16; ++ks)
                acc = __builtin_amdgcn_mfma_f32_16x16x32_bf16(afr[ks], fr2[ks], acc, 0, 0, 0);
        }

        if (h == 1) {
            #pragma unroll
            for (int j = 0; j < 4; ++j)
                red[ct * 256 + (kg * 4 + j) * 16 + c] = acc[j];
        }
        __syncthreads();

        if (h == 0) {
            float* op = out + (size_t)t * BN;
            unsigned* pbuf = ybits + (size_t)(t % 3) * (8 * 1024) + bb * 1024;
            #pragma unroll
            for (int j = 0; j < 4; ++j) {
                float z  = acc[j] + red[ct * 256 + (kg * 4 + j) * 16 + c];
                float x  = (txv[j] + z) + brv;
                float vv = DECAY_F * vreg[j] + x;
                int   sp = vv > THRESH;
                vreg[j]  = sp ? 0.f : vv;
                op[(size_t)(b0 + kg * 4 + j) * NNEUR + i0 + ct * 16 + c] = sp ? 1.f : 0.f;
                unsigned long long m = __ballot(sp != 0);
                if (c == j) {
                    unsigned u16v = (unsigned)((m >> (kg * 16)) & 0xFFFFu);
                    atomicExch(&pbuf[(kg * 4 + j) * 64 + ib * 2 + ct],
                               ((unsigned)t << 16) | u16v);
                }
            }
        }
        // no end-of-step barrier: stamp polling is the synchronization
    }
}

extern "C" void kernel_launch(void* const* d_in, const int* in_sizes, int n_in,
                              void* d_out, int out_size, void* d_ws, size_t ws_size,
                              hipStream_t stream)
{
    const float* tx = (const float*)d_in[0];
    const float* Wr = (const float*)d_in[1];
    const float* br = (const float*)d_in[2];
    float* out = (float*)d_out;
    unsigned* ybits = (unsigned*)d_ws;   // [3][8][1024] u32 = 96 KB

    const int lds_bytes = 2 * 16 * 16 * 4 + 16 * 66 * 2;   // 4160
    hipFuncSetAttribute(reinterpret_cast<const void*>(rlif_persist),
                        hipFuncAttributeMaxDynamicSharedMemorySize, lds_bytes);

    rlif_init<<<dim3(96), dim3(256), 0, stream>>>(ybits);
    rlif_persist<<<dim3(256), dim3(256), lds_bytes, stream>>>(tx, Wr, br, out, ybits);
}